// Round 11
// baseline (113.074 us; speedup 1.0000x reference)
//
#include <hip/hip_runtime.h>

// NodeEdgeProjection: out[b, e, f] = x[b, e/127, f]
// B=128, N=128, n_edges=128*127, F=64, fp32. 533 MB written, 4 MB read.
//
// Ladder (wall us): fill533 88.0 (device, plain stores) | R10 tiny+nt+1cu
// 99.8 | R3 tiny+nt 103.1 | R9 106.0 | fat+plain 106.6 | fat+nt 113.6.
// R10 confirmed the window-tightness theory (1 block/CU => 8 MB rolling
// window, -3.3 us).
//
// Round-10: single-variable bisect of the LAST untested cell -- nt on the
// tiny-block structure. nt was only ever measured on the fat structure,
// where it COST 7 us (106.6 -> 113.6); the 88 us fill floor uses plain
// stores. Mechanism: plain stores let L2 write-combine each block's 4 KB
// bursts into full dirty lines; nt bypasses L2 and issues finer HBM bursts.
// This kernel = R10 verbatim with plain stores.

typedef float f32x4 __attribute__((ext_vector_type(4)));

constexpr unsigned Bn = 128;
constexpr unsigned Nn = 128;
constexpr unsigned NE = Nn * (Nn - 1);   // 16256
constexpr unsigned F4 = 16;              // f32x4 per 64-float row

__global__ __launch_bounds__(256) void node_edge_bcast_1cu_plain(
    const f32x4* __restrict__ x, f32x4* __restrict__ out) {
    // 96 KB LDS -> at most 1 resident block per CU (160 KB pool).
    __shared__ f32x4 occupancy_pad[6144];

    const unsigned blk  = blockIdx.x;        // = b*Nn + node
    const unsigned tid  = threadIdx.x;
    const unsigned f4   = tid & (F4 - 1);    // feature quad 0..15
    const unsigned row0 = tid >> 4;          // starting replica row 0..15

    const f32x4 v = x[blk * F4 + f4];

    const unsigned b    = blk >> 7;          // / Nn
    const unsigned node = blk & (Nn - 1);    // % Nn
    f32x4* dst = out + (b * NE + node * (Nn - 1)) * F4;

    #pragma unroll
    for (unsigned r = row0; r < Nn - 1; r += 16) {
        dst[r * F4 + f4] = v;
    }

    // Keep the LDS allocation live; never executes (blockIdx range is
    // opaque to the compiler so this isn't provably dead).
    if (blk == 0xFFFFFFFFu) {
        occupancy_pad[tid] = v;
        __syncthreads();
        dst[0] = occupancy_pad[255 - tid];
    }
}

extern "C" void kernel_launch(void* const* d_in, const int* in_sizes, int n_in,
                              void* d_out, int out_size, void* d_ws, size_t ws_size,
                              hipStream_t stream) {
    const f32x4* x = (const f32x4*)d_in[0];
    f32x4* out = (f32x4*)d_out;

    node_edge_bcast_1cu_plain<<<Bn * Nn, 256, 0, stream>>>(x, out);
}

// Round 12
// 105.747 us; speedup vs baseline: 1.0693x; 1.0693x over previous
//
#include <hip/hip_runtime.h>

// NodeEdgeProjection: out[b, e, f] = x[b, e/127, f]
// B=128, N=128, n_edges=128*127, F=64, fp32. 533 MB written, 4 MB read.
//
// Ladder (wall us): fill533 88.0(dev) | R10 tiny+nt+1block/CU 99.8 |
// R3 tiny+nt 103.1 | R9 106.0 | fat+plain 106.6 | R11 tiny+plain+1cu 113.1.
// nt is an INTERACTION: helps at 1 block/CU (+13), hurts at 8/CU (-7).
// Window-tightness confirmed (R10). Residual vs fill: 64 sequential tiny
// block launches per CU, each starting with an unhidden ~200cy row load.
//
// Round-11: persistent kernel. 256 blocks (1/CU, fill's dispatch shape),
// each runs 64 iterations. INTERLEAVED pair map: iter k, block b -> pair
// k*256+b, so the grid's instantaneous writes stay in one contiguous ~8 MB
// marching window (R10's regime) with NO re-launch gaps, and the next row is
// prefetched during the current pair's 8 nt stores (hides the L2 load).

typedef float f32x4 __attribute__((ext_vector_type(4)));

constexpr unsigned Nn   = 128;
constexpr unsigned REP  = Nn - 1;          // 127 replica rows per pair
constexpr unsigned F4   = 16;              // f32x4 per 64-float row
constexpr unsigned NBLK = 256;             // 1 block per CU
constexpr unsigned ITER = 128 * 128 / NBLK; // 64 pairs per block

__global__ __launch_bounds__(256) void node_edge_persist(
    const f32x4* __restrict__ x, f32x4* __restrict__ out) {
    const unsigned tid  = threadIdx.x;
    const unsigned f4   = tid & (F4 - 1);   // feature quad 0..15
    const unsigned row0 = tid >> 4;         // starting replica row 0..15
    const unsigned b    = blockIdx.x;       // 0..255

    // Prefetch iteration 0's row.
    f32x4 v = x[b * F4 + f4];

    for (unsigned k = 0; k < ITER; ++k) {
        const unsigned pair = k * NBLK + b;

        // Prefetch next iteration's row; consumed after this iteration's
        // stores (8 nt store instructions of slack hide the L2 hit).
        f32x4 vn;
        if (k + 1 < ITER) vn = x[(pair + NBLK) * F4 + f4];

        // 127 replica rows; 16 rows per block-wide 4 KB contiguous chunk.
        f32x4* dst = out + (size_t)pair * REP * F4 + f4;
        #pragma unroll
        for (unsigned r = row0; r < REP; r += 16) {
            __builtin_nontemporal_store(v, &dst[r * F4]);
        }

        v = vn;
    }
}

extern "C" void kernel_launch(void* const* d_in, const int* in_sizes, int n_in,
                              void* d_out, int out_size, void* d_ws, size_t ws_size,
                              hipStream_t stream) {
    const f32x4* x = (const f32x4*)d_in[0];
    f32x4* out = (f32x4*)d_out;

    node_edge_persist<<<NBLK, 256, 0, stream>>>(x, out);
}